// Round 19
// baseline (39.493 us; speedup 1.0000x reference)
//
#include <hip/hip_runtime.h>

#pragma clang fp contract(off)

typedef unsigned long long u64;
typedef float f4 __attribute__((ext_vector_type(4)));

#define TOPK 5
#define WAVES 4   // waves {0,1} -> gt0, waves {2,3} -> gt1

// branchless compare-exchange on u64 keys (ascending)
#define CE(x, y) do { const u64 _a = (x), _b = (y); const bool _l = _b < _a; \
                      (x) = _l ? _b : _a; (y) = _l ? _a : _b; } while (0)

// branchless sorted-insert of nk into ascending 5-list (k0..k4)
#define INSERT(nk) do {                            \
    const u64 _n = (nk);                           \
    const bool l0 = _n < k0;                       \
    const bool l1 = _n < k1;                       \
    const bool l2 = _n < k2;                       \
    const bool l3 = _n < k3;                       \
    const bool l4 = _n < k4;                       \
    k4 = l4 ? (l3 ? k3 : _n) : k4;                 \
    k3 = l3 ? (l2 ? k2 : _n) : k3;                 \
    k2 = l2 ? (l1 ? k1 : _n) : k2;                 \
    k1 = l1 ? (l0 ? k0 : _n) : k1;                 \
    k0 = l0 ? _n : k0;                             \
} while (0)

// Markstein-refined division (bit-exact vs reference: absmax 0.0 in R3-R18)
__device__ __forceinline__ float fast_div(float a, float b) {
    float r = __builtin_amdgcn_rcpf(b);
    r = fmaf(fmaf(-b, r, 1.0f), r, r);
    float q = a * r;
    q = fmaf(fmaf(-b, q, a), r, q);
    return q;
}

// full key from precomputed cost_bbox (cb)
__device__ __forceinline__ u64 eval_rest(const f4 pb, const float cb,
                                         const f4 gb, const float g_area,
                                         const int p) {
    const float area_p = (pb.z - pb.x) * (pb.w - pb.y);
    const float ltx = fmaxf(pb.x, gb.x), lty = fmaxf(pb.y, gb.y);
    const float rbx = fminf(pb.z, gb.z), rby = fminf(pb.w, gb.w);
    const float iw = fmaxf(rbx - ltx, 0.0f), ih = fmaxf(rby - lty, 0.0f);
    const float inter = iw * ih;
    const float uni = area_p + g_area - inter;
    const float iou = fast_div(inter, uni);
    const float ex1 = fminf(pb.x, gb.x), ey1 = fminf(pb.y, gb.y);
    const float ex2 = fmaxf(pb.z, gb.z), ey2 = fmaxf(pb.w, gb.w);
    const float area_e = (ex2 - ex1) * (ey2 - ey1);
    const float giou = iou - fast_div(area_e - uni, area_e);
    const float cost = cb + (1.0f - giou);
    return ((u64)__float_as_uint(cost) << 32) | (unsigned)p;
}

__device__ __forceinline__ float bbox_l1(const f4 pb, const f4 gb) {
    return fabsf(pb.x - gb.x) + fabsf(pb.y - gb.y)
         + fabsf(pb.z - gb.z) + fabsf(pb.w - gb.w);
}

__global__ __launch_bounds__(64 * WAVES) void matcher_topk_kernel(
    const float* __restrict__ pred_box,  // [B, NP, 4]
    const float* __restrict__ gt_box,    // [B, NG, 4]
    int* __restrict__ out_pred,          // [B, NG*TOPK]
    int* __restrict__ out_gt,            // [B, NG*TOPK]
    int B, int NP, int NG)
{
    const int pairsPerB = (NG + 1) >> 1;
    const int tp = blockIdx.x;               // one block per (b, gt-pair)
    const int b  = tp / pairsPerB;
    const int j  = tp - b * pairsPerB;
    const int m0 = 2 * j;
    const bool has1 = (m0 + 1 < NG);

    const int wid  = threadIdx.x >> 6;
    const int lane = threadIdx.x & 63;
    const int myGt = wid >> 1;               // 0 or 1
    const int half = wid & 1;                // pred half

    const f4 gb = ((const f4*)gt_box)[b * NG + (myGt ? (has1 ? m0 + 1 : m0) : m0)];
    const float g_area = (gb.z - gb.x) * (gb.w - gb.y);

    const int NPm1  = NP - 1;
    const int hN    = (NP + 1) >> 1;
    const int start = half ? hN : 0;
    const int pend  = half ? NP : hN;
    // 10 groups of 256 preds per wave (2500/half); static schedule (NP=5000).

    u64 k0 = ~0ULL, k1 = ~0ULL, k2 = ~0ULL, k3 = ~0ULL, k4 = ~0ULL;

    const f4* pbase = (const f4*)pred_box + (size_t)b * NP;

// FAST load (non-tail): one address, offset-folded immediates
#define GLOADF(g, rA, rB, rC, rD) do {                                          \
    const f4* _p = pbase + (start + ((g) << 8) + lane);                         \
    asm volatile("global_load_dwordx4 %0, %1, off"             : "=v"(rA) : "v"(_p)); \
    asm volatile("global_load_dwordx4 %0, %1, off offset:1024" : "=v"(rB) : "v"(_p)); \
    asm volatile("global_load_dwordx4 %0, %1, off offset:2048" : "=v"(rC) : "v"(_p)); \
    asm volatile("global_load_dwordx4 %0, %1, off offset:3072" : "=v"(rD) : "v"(_p)); \
} while (0)

// SAFE load (tail group): per-sub clamp (dup reads of last pred; keys masked)
#define GLOADS(g, rA, rB, rC, rD) do {                                          \
    const int _i = start + ((g) << 8) + lane;                                   \
    const f4* _p0 = pbase + min(_i,       NPm1);                                \
    const f4* _p1 = pbase + min(_i + 64,  NPm1);                                \
    const f4* _p2 = pbase + min(_i + 128, NPm1);                                \
    const f4* _p3 = pbase + min(_i + 192, NPm1);                                \
    asm volatile("global_load_dwordx4 %0, %1, off" : "=v"(rA) : "v"(_p0));      \
    asm volatile("global_load_dwordx4 %0, %1, off" : "=v"(rB) : "v"(_p1));      \
    asm volatile("global_load_dwordx4 %0, %1, off" : "=v"(rC) : "v"(_p2));      \
    asm volatile("global_load_dwordx4 %0, %1, off" : "=v"(rD) : "v"(_p3));      \
} while (0)

// counted wait + sched fence (rule #18)
#define W(n) do {                                         \
    asm volatile("s_waitcnt vmcnt(" #n ")");              \
    __builtin_amdgcn_sched_barrier(0);                    \
} while (0)

// unscreened group: 4 evals -> sort4 -> bitonic lower-5 merge into top5
#define PROCG(g, rA, rB, rC, rD) do {                                        \
    const int _i0 = start + ((g) << 8) + lane;                               \
    u64 kA = eval_rest(rA, bbox_l1(rA, gb), gb, g_area, _i0);                \
    u64 kB = eval_rest(rB, bbox_l1(rB, gb), gb, g_area, _i0 + 64);           \
    u64 kC = eval_rest(rC, bbox_l1(rC, gb), gb, g_area, _i0 + 128);          \
    u64 kD = eval_rest(rD, bbox_l1(rD, gb), gb, g_area, _i0 + 192);          \
    CE(kA, kB); CE(kC, kD); CE(kA, kC); CE(kB, kD); CE(kB, kC);              \
    u64 n0 = k0;                                                             \
    u64 n1 = k1 < kD ? k1 : kD;                                              \
    u64 n2 = k2 < kC ? k2 : kC;                                              \
    u64 n3 = k3 < kB ? k3 : kB;                                              \
    u64 n4 = k4 < kA ? k4 : kA;                                              \
    CE(n0, n1); CE(n3, n4); CE(n2, n4); CE(n2, n3); CE(n1, n4);              \
    CE(n0, n3); CE(n0, n2); CE(n1, n3); CE(n1, n2);                          \
    k0 = n0; k1 = n1; k2 = n2; k3 = n3; k4 = n4;                             \
} while (0)

// screened sub-batch: cheap L1 lower-bound vs wave-wide threshold (SGPR).
// cost >= cost_bbox > thr  =>  provably outside final top-5 (strict, exact).
// Wave-uniform branch; taken path evaluates+inserts ALL lanes (correct).
#define PROCS(pb_, idx_, TAIL) do {                                          \
    const float _cb = bbox_l1(pb_, gb);                                      \
    bool _pass = (__float_as_uint(_cb) <= thr_bits);                         \
    if (TAIL) _pass = _pass && ((idx_) < pend);                              \
    if (__any((int)_pass)) {                                                 \
        u64 _k = eval_rest(pb_, _cb, gb, g_area, (idx_));                    \
        if (TAIL) _k = ((idx_) < pend) ? _k : ~0ULL;                         \
        INSERT(_k);                                                          \
    }                                                                        \
} while (0)

#define PROCSG(g, TAIL, rA, rB, rC, rD) do {                                 \
    const int _i0 = start + ((g) << 8) + lane;                               \
    PROCS(rA, _i0,       TAIL);                                              \
    PROCS(rB, _i0 + 64,  TAIL);                                              \
    PROCS(rC, _i0 + 128, TAIL);                                              \
    PROCS(rD, _i0 + 192, TAIL);                                              \
} while (0)

    f4 xA, xB, xC, xD;
    f4 yA, yB, yC, yD;
    f4 zA, zB, zC, zD;
    f4 uA, uB, uC, uD;

    GLOADF(0, xA, xB, xC, xD);
    GLOADF(1, yA, yB, yC, yD);
    GLOADF(2, zA, zB, zC, zD);
    GLOADF(3, uA, uB, uC, uD);

    unsigned thr_bits = 0xFFFFFFFFu;

    // phase 0: groups 0,1 (unscreened — building the threshold basis)
    W(8);
    PROCG(0, xA, xB, xC, xD);
    PROCG(1, yA, yB, yC, yD);
    GLOADF(4, xA, xB, xC, xD);
    GLOADF(5, yA, yB, yC, yD);

    // phase 1: group 2 unscreened; then wave-wide threshold; group 3 screened
    W(8);
    PROCG(2, zA, zB, zC, zD);
    {
        // butterfly on a COPY (in-place would duplicate keys across lanes and
        // poison the final merge) -> all lanes hold wave top-5 of 768 cands
        u64 c0 = k0, c1 = k1, c2 = k2, c3 = k3, c4 = k4;
        #pragma unroll
        for (int off = 1; off < 64; off <<= 1) {
            const u64 b0 = __shfl_xor(c0, off);
            const u64 b1 = __shfl_xor(c1, off);
            const u64 b2 = __shfl_xor(c2, off);
            const u64 b3 = __shfl_xor(c3, off);
            const u64 b4 = __shfl_xor(c4, off);
            u64 m0_ = c0 < b4 ? c0 : b4;
            u64 m1_ = c1 < b3 ? c1 : b3;
            u64 m2_ = c2 < b2 ? c2 : b2;
            u64 m3_ = c3 < b1 ? c3 : b1;
            u64 m4_ = c4 < b0 ? c4 : b0;
            CE(m0_, m1_); CE(m3_, m4_); CE(m2_, m4_); CE(m2_, m3_); CE(m1_, m4_);
            CE(m0_, m3_); CE(m0_, m2_); CE(m1_, m3_); CE(m1_, m2_);
            c0 = m0_; c1 = m1_; c2 = m2_; c3 = m3_; c4 = m4_;
        }
        thr_bits = __builtin_amdgcn_readfirstlane((unsigned)(c4 >> 32));
    }
    PROCSG(3, false, uA, uB, uC, uD);
    GLOADF(6, zA, zB, zC, zD);
    GLOADF(7, uA, uB, uC, uD);

    // phase 2: groups 4,5 screened
    W(8);
    PROCSG(4, false, xA, xB, xC, xD);
    PROCSG(5, false, yA, yB, yC, yD);
    GLOADF(8, xA, xB, xC, xD);
    GLOADS(9, yA, yB, yC, yD);

    // phase 3: groups 6,7 screened
    W(8);
    PROCSG(6, false, zA, zB, zC, zD);
    PROCSG(7, false, uA, uB, uC, uD);

    // phase 4: groups 8,9 screened; nothing in flight after (no R11 hazard)
    W(0);
    PROCSG(8, false, xA, xB, xC, xD);
    PROCSG(9, true,  yA, yB, yC, yD);

#undef GLOADF
#undef GLOADS
#undef W
#undef PROCG
#undef PROCS
#undef PROCSG

    // final wave butterfly: merge sorted 5-lists across all 64 lanes
    #pragma unroll
    for (int off = 1; off < 64; off <<= 1) {
        const u64 b0 = __shfl_xor(k0, off);
        const u64 b1 = __shfl_xor(k1, off);
        const u64 b2 = __shfl_xor(k2, off);
        const u64 b3 = __shfl_xor(k3, off);
        const u64 b4 = __shfl_xor(k4, off);
        u64 m0_ = k0 < b4 ? k0 : b4;
        u64 m1_ = k1 < b3 ? k1 : b3;
        u64 m2_ = k2 < b2 ? k2 : b2;
        u64 m3_ = k3 < b1 ? k3 : b1;
        u64 m4_ = k4 < b0 ? k4 : b0;
        CE(m0_, m1_); CE(m3_, m4_); CE(m2_, m4_); CE(m2_, m3_); CE(m1_, m4_);
        CE(m0_, m3_); CE(m0_, m2_); CE(m1_, m3_); CE(m1_, m2_);
        k0 = m0_; k1 = m1_; k2 = m2_; k3 = m3_; k4 = m4_;
    }

    // cross-wave merge via LDS: per gt, 2 sorted 5-lists -> final 5
    __shared__ u64 lds[WAVES][TOPK];
    if (lane == 0) {
        lds[wid][0] = k0; lds[wid][1] = k1; lds[wid][2] = k2;
        lds[wid][3] = k3; lds[wid][4] = k4;
    }
    __syncthreads();

    if (threadIdx.x < 2) {
        const int which = threadIdx.x;       // gt0 / gt1
        if (which == 0 || has1) {
            const int mm = m0 + which;
            int h0 = 0, h1 = 0;
            const int base = (b * NG + mm) * TOPK;
            #pragma unroll
            for (int r = 0; r < TOPK; ++r) {
                const u64 v0 = lds[which * 2][h0];
                const u64 v1 = lds[which * 2 + 1][h1];
                const bool t = v0 < v1;
                const u64 best = t ? v0 : v1;
                h0 += t; h1 += !t;
                out_pred[base + r] = (int)(unsigned)(best & 0xFFFFFFFFu);
                out_gt[base + r]   = mm;
            }
        }
    }
}

extern "C" void kernel_launch(void* const* d_in, const int* in_sizes, int n_in,
                              void* d_out, int out_size, void* d_ws, size_t ws_size,
                              hipStream_t stream) {
    const float* pred_box = (const float*)d_in[0];   // [B, NP, 4]
    const float* gt_box   = (const float*)d_in[2];   // [B, NG, 4]

    const int NP = 5000;
    const int B  = in_sizes[1] / NP;                 // pred_obj is [B, NP]
    const int NG = in_sizes[3] / B;                  // gt_obj is [B, NG]

    int* out_pred = (int*)d_out;
    int* out_gt   = out_pred + B * NG * TOPK;

    const int pairsPerB = (NG + 1) >> 1;
    const int blocks = B * pairsPerB;                // one block per gt-pair
    hipLaunchKernelGGL(matcher_topk_kernel, dim3(blocks), dim3(64 * WAVES), 0, stream,
                       pred_box, gt_box, out_pred, out_gt, B, NP, NG);
}

// Round 20
// 35.249 us; speedup vs baseline: 1.1204x; 1.1204x over previous
//
#include <hip/hip_runtime.h>

#pragma clang fp contract(off)

typedef unsigned long long u64;
typedef float f4 __attribute__((ext_vector_type(4)));

#define TOPK 5
#define WAVES 4   // waves {0,1} -> gt0, waves {2,3} -> gt1

// branchless compare-exchange on u64 keys (ascending)
#define CE(x, y) do { const u64 _a = (x), _b = (y); const bool _l = _b < _a; \
                      (x) = _l ? _b : _a; (y) = _l ? _a : _b; } while (0)

// Markstein-refined division (bit-exact vs reference: absmax 0.0 in R3-R19)
__device__ __forceinline__ float fast_div(float a, float b) {
    float r = __builtin_amdgcn_rcpf(b);
    r = fmaf(fmaf(-b, r, 1.0f), r, r);
    float q = a * r;
    q = fmaf(fmaf(-b, q, a), r, q);
    return q;
}

__device__ __forceinline__ u64 eval_key(const f4 pb, const f4 gb,
                                        const float g_area, const int p) {
    const float area_p = (pb.z - pb.x) * (pb.w - pb.y);
    const float cost_bbox = fabsf(pb.x - gb.x) + fabsf(pb.y - gb.y)
                          + fabsf(pb.z - gb.z) + fabsf(pb.w - gb.w);
    const float ltx = fmaxf(pb.x, gb.x), lty = fmaxf(pb.y, gb.y);
    const float rbx = fminf(pb.z, gb.z), rby = fminf(pb.w, gb.w);
    const float iw = fmaxf(rbx - ltx, 0.0f), ih = fmaxf(rby - lty, 0.0f);
    const float inter = iw * ih;
    const float uni = area_p + g_area - inter;
    const float iou = fast_div(inter, uni);
    const float ex1 = fminf(pb.x, gb.x), ey1 = fminf(pb.y, gb.y);
    const float ex2 = fmaxf(pb.z, gb.z), ey2 = fmaxf(pb.w, gb.w);
    const float area_e = (ex2 - ex1) * (ey2 - ey1);
    const float giou = iou - fast_div(area_e - uni, area_e);
    const float cost = cost_bbox + (1.0f - giou);
    return ((u64)__float_as_uint(cost) << 32) | (unsigned)p;
}

__global__ __launch_bounds__(64 * WAVES) void matcher_topk_kernel(
    const float* __restrict__ pred_box,  // [B, NP, 4]
    const float* __restrict__ gt_box,    // [B, NG, 4]
    int* __restrict__ out_pred,          // [B, NG*TOPK]
    int* __restrict__ out_gt,            // [B, NG*TOPK]
    int B, int NP, int NG)
{
    const int pairsPerB = (NG + 1) >> 1;
    const int tp = blockIdx.x;               // one block per (b, gt-pair)
    const int b  = tp / pairsPerB;
    const int j  = tp - b * pairsPerB;
    const int m0 = 2 * j;
    const bool has1 = (m0 + 1 < NG);

    const int wid  = threadIdx.x >> 6;
    const int lane = threadIdx.x & 63;
    const int myGt = wid >> 1;               // 0 or 1
    const int half = wid & 1;                // pred half

    const f4 gb = ((const f4*)gt_box)[b * NG + (myGt ? (has1 ? m0 + 1 : m0) : m0)];
    const float g_area = (gb.z - gb.x) * (gb.w - gb.y);

    const int NPm1  = NP - 1;
    const int hN    = (NP + 1) >> 1;
    const int start = half ? hN : 0;
    const int pend  = half ? NP : hN;
    // 10 groups of 256 preds per wave (2500/half); static schedule (NP=5000).

    // TWO independent sorted-5 states: a* <- even groups, c* <- odd groups.
    // Breaks the state-carried merge dependency chain between consecutive
    // groups in a phase (R18's two merges serialized on one k-state).
    u64 a0 = ~0ULL, a1 = ~0ULL, a2 = ~0ULL, a3 = ~0ULL, a4 = ~0ULL;
    u64 c0 = ~0ULL, c1 = ~0ULL, c2 = ~0ULL, c3 = ~0ULL, c4 = ~0ULL;

    const f4* pbase = (const f4*)pred_box + (size_t)b * NP;

// FAST load (non-tail): one address, offset-folded immediates
#define GLOADF(g, rA, rB, rC, rD) do {                                          \
    const f4* _p = pbase + (start + ((g) << 8) + lane);                         \
    asm volatile("global_load_dwordx4 %0, %1, off"             : "=v"(rA) : "v"(_p)); \
    asm volatile("global_load_dwordx4 %0, %1, off offset:1024" : "=v"(rB) : "v"(_p)); \
    asm volatile("global_load_dwordx4 %0, %1, off offset:2048" : "=v"(rC) : "v"(_p)); \
    asm volatile("global_load_dwordx4 %0, %1, off offset:3072" : "=v"(rD) : "v"(_p)); \
} while (0)

// SAFE load (tail group): per-sub clamp (dup reads of last pred; keys masked)
#define GLOADS(g, rA, rB, rC, rD) do {                                          \
    const int _i = start + ((g) << 8) + lane;                                   \
    const f4* _p0 = pbase + min(_i,       NPm1);                                \
    const f4* _p1 = pbase + min(_i + 64,  NPm1);                                \
    const f4* _p2 = pbase + min(_i + 128, NPm1);                                \
    const f4* _p3 = pbase + min(_i + 192, NPm1);                                \
    asm volatile("global_load_dwordx4 %0, %1, off" : "=v"(rA) : "v"(_p0));      \
    asm volatile("global_load_dwordx4 %0, %1, off" : "=v"(rB) : "v"(_p1));      \
    asm volatile("global_load_dwordx4 %0, %1, off" : "=v"(rC) : "v"(_p2));      \
    asm volatile("global_load_dwordx4 %0, %1, off" : "=v"(rD) : "v"(_p3));      \
} while (0)

// counted wait + sched fence (rule #18)
#define W(n) do {                                         \
    asm volatile("s_waitcnt vmcnt(" #n ")");              \
    __builtin_amdgcn_sched_barrier(0);                    \
} while (0)

// 4 evals (ILP) -> (tail: mask) -> sort4 -> bitonic lower-5 merge into the
// GIVEN state (s0..s4) — states alternate per group for chain independence
#define PROCG(g, TAIL, rA, rB, rC, rD, s0, s1, s2, s3, s4) do {              \
    const int _i0 = start + ((g) << 8) + lane;                               \
    u64 kA = eval_key(rA, gb, g_area, _i0);                                  \
    u64 kB = eval_key(rB, gb, g_area, _i0 + 64);                             \
    u64 kC = eval_key(rC, gb, g_area, _i0 + 128);                            \
    u64 kD = eval_key(rD, gb, g_area, _i0 + 192);                            \
    if (TAIL) {                                                              \
        kA = (_i0       < pend) ? kA : ~0ULL;                                \
        kB = (_i0 + 64  < pend) ? kB : ~0ULL;                                \
        kC = (_i0 + 128 < pend) ? kC : ~0ULL;                                \
        kD = (_i0 + 192 < pend) ? kD : ~0ULL;                                \
    }                                                                        \
    CE(kA, kB); CE(kC, kD); CE(kA, kC); CE(kB, kD); CE(kB, kC);              \
    u64 n0 = s0;                                                             \
    u64 n1 = s1 < kD ? s1 : kD;                                              \
    u64 n2 = s2 < kC ? s2 : kC;                                              \
    u64 n3 = s3 < kB ? s3 : kB;                                              \
    u64 n4 = s4 < kA ? s4 : kA;                                              \
    CE(n0, n1); CE(n3, n4); CE(n2, n4); CE(n2, n3); CE(n1, n4);              \
    CE(n0, n3); CE(n0, n2); CE(n1, n3); CE(n1, n2);                          \
    s0 = n0; s1 = n1; s2 = n2; s3 = n3; s4 = n4;                             \
} while (0)

    f4 xA, xB, xC, xD;
    f4 yA, yB, yC, yD;
    f4 zA, zB, zC, zD;
    f4 uA, uB, uC, uD;

    GLOADF(0, xA, xB, xC, xD);
    GLOADF(1, yA, yB, yC, yD);
    GLOADF(2, zA, zB, zC, zD);
    GLOADF(3, uA, uB, uC, uD);

    // phase 0: groups 0->a, 1->c (independent merge chains)
    W(8);
    PROCG(0, false, xA, xB, xC, xD, a0, a1, a2, a3, a4);
    PROCG(1, false, yA, yB, yC, yD, c0, c1, c2, c3, c4);
    GLOADF(4, xA, xB, xC, xD);
    GLOADF(5, yA, yB, yC, yD);
    // phase 1: groups 2->a, 3->c
    W(8);
    PROCG(2, false, zA, zB, zC, zD, a0, a1, a2, a3, a4);
    PROCG(3, false, uA, uB, uC, uD, c0, c1, c2, c3, c4);
    GLOADF(6, zA, zB, zC, zD);
    GLOADF(7, uA, uB, uC, uD);
    // phase 2: groups 4->a, 5->c
    W(8);
    PROCG(4, false, xA, xB, xC, xD, a0, a1, a2, a3, a4);
    PROCG(5, false, yA, yB, yC, yD, c0, c1, c2, c3, c4);
    GLOADF(8, xA, xB, xC, xD);
    GLOADS(9, yA, yB, yC, yD);
    // phase 3: groups 6->a, 7->c
    W(8);
    PROCG(6, false, zA, zB, zC, zD, a0, a1, a2, a3, a4);
    PROCG(7, false, uA, uB, uC, uD, c0, c1, c2, c3, c4);
    // phase 4: groups 8->a, 9->c; nothing in flight after (no R11 hazard)
    W(0);
    PROCG(8, false, xA, xB, xC, xD, a0, a1, a2, a3, a4);
    PROCG(9, true,  yA, yB, yC, yD, c0, c1, c2, c3, c4);

#undef GLOADF
#undef GLOADS
#undef W
#undef PROCG

    // combine the two states: lower-5 bitonic merge of sorted a and sorted c
    u64 k0, k1, k2, k3, k4;
    {
        k0 = a0 < c4 ? a0 : c4;
        k1 = a1 < c3 ? a1 : c3;
        k2 = a2 < c2 ? a2 : c2;
        k3 = a3 < c1 ? a3 : c1;
        k4 = a4 < c0 ? a4 : c0;
        CE(k0, k1); CE(k3, k4); CE(k2, k4); CE(k2, k3); CE(k1, k4);
        CE(k0, k3); CE(k0, k2); CE(k1, k3); CE(k1, k2);
    }

    // wave butterfly: merge sorted 5-lists across all 64 lanes
    #pragma unroll
    for (int off = 1; off < 64; off <<= 1) {
        const u64 b0 = __shfl_xor(k0, off);
        const u64 b1 = __shfl_xor(k1, off);
        const u64 b2 = __shfl_xor(k2, off);
        const u64 b3 = __shfl_xor(k3, off);
        const u64 b4 = __shfl_xor(k4, off);
        u64 m0_ = k0 < b4 ? k0 : b4;
        u64 m1_ = k1 < b3 ? k1 : b3;
        u64 m2_ = k2 < b2 ? k2 : b2;
        u64 m3_ = k3 < b1 ? k3 : b1;
        u64 m4_ = k4 < b0 ? k4 : b0;
        CE(m0_, m1_); CE(m3_, m4_); CE(m2_, m4_); CE(m2_, m3_); CE(m1_, m4_);
        CE(m0_, m3_); CE(m0_, m2_); CE(m1_, m3_); CE(m1_, m2_);
        k0 = m0_; k1 = m1_; k2 = m2_; k3 = m3_; k4 = m4_;
    }

    // cross-wave merge via LDS: per gt, 2 sorted 5-lists -> final 5
    __shared__ u64 lds[WAVES][TOPK];
    if (lane == 0) {
        lds[wid][0] = k0; lds[wid][1] = k1; lds[wid][2] = k2;
        lds[wid][3] = k3; lds[wid][4] = k4;
    }
    __syncthreads();

    if (threadIdx.x < 2) {
        const int which = threadIdx.x;       // gt0 / gt1
        if (which == 0 || has1) {
            const int mm = m0 + which;
            int h0 = 0, h1 = 0;
            const int base = (b * NG + mm) * TOPK;
            #pragma unroll
            for (int r = 0; r < TOPK; ++r) {
                const u64 v0 = lds[which * 2][h0];
                const u64 v1 = lds[which * 2 + 1][h1];
                const bool t = v0 < v1;
                const u64 best = t ? v0 : v1;
                h0 += t; h1 += !t;
                out_pred[base + r] = (int)(unsigned)(best & 0xFFFFFFFFu);
                out_gt[base + r]   = mm;
            }
        }
    }
}

extern "C" void kernel_launch(void* const* d_in, const int* in_sizes, int n_in,
                              void* d_out, int out_size, void* d_ws, size_t ws_size,
                              hipStream_t stream) {
    const float* pred_box = (const float*)d_in[0];   // [B, NP, 4]
    const float* gt_box   = (const float*)d_in[2];   // [B, NG, 4]

    const int NP = 5000;
    const int B  = in_sizes[1] / NP;                 // pred_obj is [B, NP]
    const int NG = in_sizes[3] / B;                  // gt_obj is [B, NG]

    int* out_pred = (int*)d_out;
    int* out_gt   = out_pred + B * NG * TOPK;

    const int pairsPerB = (NG + 1) >> 1;
    const int blocks = B * pairsPerB;                // one block per gt-pair
    hipLaunchKernelGGL(matcher_topk_kernel, dim3(blocks), dim3(64 * WAVES), 0, stream,
                       pred_box, gt_box, out_pred, out_gt, B, NP, NG);
}